// Round 1
// baseline (215.762 us; speedup 1.0000x reference)
//
#include <hip/hip_runtime.h>
#include <hip/hip_bf16.h>
#include <cstdint>
#include <cstddef>

#define NE 8
#define NH 1024
#define NF 2048
#define NT 8192
#define TPE (NT / NE)   // 1024

typedef uint16_t u16;
typedef uint32_t u32;
typedef __attribute__((ext_vector_type(8))) __bf16 bf16x8;
typedef __attribute__((ext_vector_type(4))) float f32x4;

__device__ __forceinline__ u16 f2bf_rn(float f) {
  u32 u = __float_as_uint(f);
  u32 r = (u + 0x7fffu + ((u >> 16) & 1u)) >> 16;
  return (u16)r;
}

// ---------------- fp32 -> bf16 elementwise convert (RNE) ----------------
__global__ void cvt_f32_bf16(const float* __restrict__ in, u16* __restrict__ out, int n) {
  int i = (blockIdx.x * blockDim.x + threadIdx.x) * 4;
  if (i < n) {
    float4 v = *reinterpret_cast<const float4*>(in + i);
    ushort4 o;
    o.x = f2bf_rn(v.x);
    o.y = f2bf_rn(v.y);
    o.z = f2bf_rn(v.z);
    o.w = f2bf_rn(v.w);
    *reinterpret_cast<ushort4*>(out + i) = o;
  }
}

// ---------------- w2 [E][F][H] fp32 -> w2t [E][H][F] bf16 ----------------
__global__ void transpose_w2(const float* __restrict__ w2, u16* __restrict__ w2t) {
  __shared__ float tile[32][33];
  const int e = blockIdx.z;
  const int h0 = blockIdx.x * 32;
  const int f0 = blockIdx.y * 32;
  const int tx = threadIdx.x, ty = threadIdx.y;  // 32 x 8
  const float* src = w2 + ((size_t)e * NF + f0) * NH + h0;
#pragma unroll
  for (int i = 0; i < 4; i++) {
    int r = ty + i * 8;
    tile[r][tx] = src[(size_t)r * NH + tx];
  }
  __syncthreads();
  u16* dst = w2t + ((size_t)e * NH + h0) * NF + f0;
#pragma unroll
  for (int i = 0; i < 4; i++) {
    int r = ty + i * 8;
    dst[(size_t)r * NF + tx] = f2bf_rn(tile[tx][r]);
  }
}

// ---------------- async global->LDS staging helpers ----------------
__device__ __forceinline__ void async_lds16(const u16* g, const u16* lds) {
  __builtin_amdgcn_global_load_lds(
      (const __attribute__((address_space(1))) u32*)g,
      (__attribute__((address_space(3))) u32*)lds, 16, 0, 0);
}

// stage a [128 rows][32 cols] bf16 tile; global row-major with leading dim ld
__device__ __forceinline__ void stage_tile(const u16* __restrict__ g_base, size_t ld,
                                           const u16* lds_base, int tid) {
#pragma unroll
  for (int p = 0; p < 2; p++) {
    int eo = (p * 256 + tid) * 8;        // element offset within 128x32 tile
    int row = eo >> 5;
    int col = eo & 31;
    async_lds16(g_base + (size_t)row * ld + col, lds_base + eo);
  }
}

// ---------------- GEMM1: h1/h2 + GLU epilogue ----------------
// A = x_bf [T][H] row-major (K-contig), B1 = w1_bf [E][F][H], B2 = v1_bf.
// g[t][f] = gelu_erf(h1) * h2, stored bf16.
__launch_bounds__(256, 2)
__global__ void glu_gemm(const u16* __restrict__ xb, const u16* __restrict__ w1b,
                         const u16* __restrict__ v1b, u16* __restrict__ gb) {
  __shared__ __align__(16) u16 As[128 * 32];
  __shared__ __align__(16) u16 Bs1[128 * 32];
  __shared__ __align__(16) u16 Bs2[128 * 32];

  const int e = blockIdx.z;
  const int m0 = e * TPE + blockIdx.y * 128;   // global token row
  const int n0 = blockIdx.x * 128;             // f column
  const int tid = threadIdx.x;
  const int lane = tid & 63;
  const int wid = tid >> 6;
  const int wr = (wid >> 1) * 64;     // wave row offset in tile
  const int wc = (wid & 1) * 64;      // wave col offset in tile

  const u16* Ag = xb + (size_t)m0 * NH;
  const u16* B1g = w1b + ((size_t)e * NF + n0) * NH;
  const u16* B2g = v1b + ((size_t)e * NF + n0) * NH;

  f32x4 acc1[4][4] = {};
  f32x4 acc2[4][4] = {};

  const int fr = lane & 15;
  const int kb = (lane >> 4) * 8;

  for (int k0 = 0; k0 < NH; k0 += 32) {
    __syncthreads();
    stage_tile(Ag + k0, NH, As, tid);
    stage_tile(B1g + k0, NH, Bs1, tid);
    stage_tile(B2g + k0, NH, Bs2, tid);
    __syncthreads();

    bf16x8 a[4], b1[4], b2[4];
#pragma unroll
    for (int m = 0; m < 4; m++)
      a[m] = *reinterpret_cast<const bf16x8*>(&As[(wr + m * 16 + fr) * 32 + kb]);
#pragma unroll
    for (int n = 0; n < 4; n++) {
      b1[n] = *reinterpret_cast<const bf16x8*>(&Bs1[(wc + n * 16 + fr) * 32 + kb]);
      b2[n] = *reinterpret_cast<const bf16x8*>(&Bs2[(wc + n * 16 + fr) * 32 + kb]);
    }
#pragma unroll
    for (int m = 0; m < 4; m++)
#pragma unroll
      for (int n = 0; n < 4; n++) {
        acc1[m][n] = __builtin_amdgcn_mfma_f32_16x16x32_bf16(a[m], b1[n], acc1[m][n], 0, 0, 0);
        acc2[m][n] = __builtin_amdgcn_mfma_f32_16x16x32_bf16(a[m], b2[n], acc2[m][n], 0, 0, 0);
      }
  }

  const int rq = (lane >> 4) * 4;
#pragma unroll
  for (int m = 0; m < 4; m++)
#pragma unroll
    for (int n = 0; n < 4; n++)
#pragma unroll
      for (int r = 0; r < 4; r++) {
        int grow = m0 + wr + m * 16 + rq + r;
        int gcol = n0 + wc + n * 16 + fr;
        float h1 = acc1[m][n][r];
        float h2 = acc2[m][n][r];
        float g = 0.5f * h1 * (1.0f + erff(h1 * 0.70710678118654752f)) * h2;
        gb[(size_t)grow * NF + gcol] = f2bf_rn(g);
      }
}

// ---------------- GEMM2: out = g @ w2  (w2t is [E][H][F], K-contig) ----------------
__launch_bounds__(256, 2)
__global__ void down_gemm(const u16* __restrict__ gb, const u16* __restrict__ w2tb,
                          float* __restrict__ out) {
  __shared__ __align__(16) u16 As[128 * 32];
  __shared__ __align__(16) u16 Bs[128 * 32];

  const int e = blockIdx.z;
  const int m0 = e * TPE + blockIdx.y * 128;
  const int n0 = blockIdx.x * 128;   // h column
  const int tid = threadIdx.x;
  const int lane = tid & 63;
  const int wid = tid >> 6;
  const int wr = (wid >> 1) * 64;
  const int wc = (wid & 1) * 64;

  const u16* Ag = gb + (size_t)m0 * NF;
  const u16* Bg = w2tb + ((size_t)e * NH + n0) * NF;

  f32x4 acc[4][4] = {};

  const int fr = lane & 15;
  const int kb = (lane >> 4) * 8;

  for (int k0 = 0; k0 < NF; k0 += 32) {
    __syncthreads();
    stage_tile(Ag + k0, NF, As, tid);
    stage_tile(Bg + k0, NF, Bs, tid);
    __syncthreads();

    bf16x8 a[4], b[4];
#pragma unroll
    for (int m = 0; m < 4; m++)
      a[m] = *reinterpret_cast<const bf16x8*>(&As[(wr + m * 16 + fr) * 32 + kb]);
#pragma unroll
    for (int n = 0; n < 4; n++)
      b[n] = *reinterpret_cast<const bf16x8*>(&Bs[(wc + n * 16 + fr) * 32 + kb]);
#pragma unroll
    for (int m = 0; m < 4; m++)
#pragma unroll
      for (int n = 0; n < 4; n++)
        acc[m][n] = __builtin_amdgcn_mfma_f32_16x16x32_bf16(a[m], b[n], acc[m][n], 0, 0, 0);
  }

  const int rq = (lane >> 4) * 4;
#pragma unroll
  for (int m = 0; m < 4; m++)
#pragma unroll
    for (int n = 0; n < 4; n++)
#pragma unroll
      for (int r = 0; r < 4; r++) {
        int grow = m0 + wr + m * 16 + rq + r;
        int gcol = n0 + wc + n * 16 + fr;
        out[(size_t)grow * NH + gcol] = acc[m][n][r];
      }
}

// ---------------- launch ----------------
extern "C" void kernel_launch(void* const* d_in, const int* in_sizes, int n_in,
                              void* d_out, int out_size, void* d_ws, size_t ws_size,
                              hipStream_t stream) {
  const float* x = (const float*)d_in[0];
  // d_in[1] = expert_idx (balanced, sorted — not needed)
  const float* w1 = (const float*)d_in[2];
  const float* v1 = (const float*)d_in[3];
  const float* w2 = (const float*)d_in[4];
  float* out = (float*)d_out;

  char* ws = (char*)d_ws;
  u16* xb   = (u16*)(ws);                                  // 16 MB
  u16* w1b  = (u16*)(ws + (size_t)16 * 1024 * 1024);       // 32 MB
  u16* v1b  = (u16*)(ws + (size_t)48 * 1024 * 1024);       // 32 MB
  u16* w2tb = (u16*)(ws + (size_t)80 * 1024 * 1024);       // 32 MB
  u16* gb   = (u16*)(ws + (size_t)112 * 1024 * 1024);      // 32 MB

  const int nx = NT * NH;          // 8M
  const int nw = NE * NF * NH;     // 16M

  cvt_f32_bf16<<<nx / 4 / 256, 256, 0, stream>>>(x, xb, nx);
  cvt_f32_bf16<<<nw / 4 / 256, 256, 0, stream>>>(w1, w1b, nw);
  cvt_f32_bf16<<<nw / 4 / 256, 256, 0, stream>>>(v1, v1b, nw);
  transpose_w2<<<dim3(NH / 32, NF / 32, NE), dim3(32, 8, 1), 0, stream>>>(w2, w2tb);

  glu_gemm<<<dim3(NF / 128, TPE / 128, NE), 256, 0, stream>>>(xb, w1b, v1b, gb);
  down_gemm<<<dim3(NH / 128, TPE / 128, NE), 256, 0, stream>>>(gb, w2tb, out);
}

// Round 2
// 206.879 us; speedup vs baseline: 1.0429x; 1.0429x over previous
//
#include <hip/hip_runtime.h>
#include <hip/hip_bf16.h>
#include <cstdint>
#include <cstddef>

#define NE 8
#define NH 1024
#define NF 2048
#define NT 8192
#define TPE (NT / NE)   // 1024
#define NKT (NH / 64)   // 16 K-tiles for the GLU gemm

typedef uint16_t u16;
typedef uint32_t u32;
typedef __attribute__((ext_vector_type(8))) __bf16 bf16x8;
typedef __attribute__((ext_vector_type(4))) float f32x4;

__device__ __forceinline__ u16 f2bf_rn(float f) {
  u32 u = __float_as_uint(f);
  u32 r = (u + 0x7fffu + ((u >> 16) & 1u)) >> 16;
  return (u16)r;
}

// ---------------- fp32 -> bf16 elementwise convert (RNE) ----------------
__global__ void cvt_f32_bf16(const float* __restrict__ in, u16* __restrict__ out, int n) {
  int i = (blockIdx.x * blockDim.x + threadIdx.x) * 4;
  if (i < n) {
    float4 v = *reinterpret_cast<const float4*>(in + i);
    ushort4 o;
    o.x = f2bf_rn(v.x);
    o.y = f2bf_rn(v.y);
    o.z = f2bf_rn(v.z);
    o.w = f2bf_rn(v.w);
    *reinterpret_cast<ushort4*>(out + i) = o;
  }
}

// ------- pack w1/v1 -> B_cat[e][4096][1024] bf16, 16-col interleave -------
// B_cat row j (per expert): p=j>>5, q=(j>>4)&1, c=j&15 ->
//   src = (q ? v1 : w1)[e][p*16+c][:]
__global__ void pack_b(const float* __restrict__ w1, const float* __restrict__ v1,
                       u16* __restrict__ bc) {
  int j = blockIdx.x;              // 0 .. NE*4096-1
  int e = j >> 12;
  int r = j & 4095;
  int p = r >> 5;
  int q = (r >> 4) & 1;
  int c = r & 15;
  const float* src = (q ? v1 : w1) + ((size_t)e * NF + p * 16 + c) * NH;
  u16* dst = bc + (size_t)j * NH;
  int i = threadIdx.x * 4;
  float4 v = *reinterpret_cast<const float4*>(src + i);
  ushort4 o;
  o.x = f2bf_rn(v.x);
  o.y = f2bf_rn(v.y);
  o.z = f2bf_rn(v.z);
  o.w = f2bf_rn(v.w);
  *reinterpret_cast<ushort4*>(dst + i) = o;
}

// ---------------- w2 [E][F][H] fp32 -> w2t [E][H][F] bf16 ----------------
__global__ void transpose_w2(const float* __restrict__ w2, u16* __restrict__ w2t) {
  __shared__ float tile[32][33];
  const int e = blockIdx.z;
  const int h0 = blockIdx.x * 32;
  const int f0 = blockIdx.y * 32;
  const int tx = threadIdx.x, ty = threadIdx.y;  // 32 x 8
  const float* src = w2 + ((size_t)e * NF + f0) * NH + h0;
#pragma unroll
  for (int i = 0; i < 4; i++) {
    int r = ty + i * 8;
    tile[r][tx] = src[(size_t)r * NH + tx];
  }
  __syncthreads();
  u16* dst = w2t + ((size_t)e * NH + h0) * NF + f0;
#pragma unroll
  for (int i = 0; i < 4; i++) {
    int r = ty + i * 8;
    dst[(size_t)r * NF + tx] = f2bf_rn(tile[tx][r]);
  }
}

// ---------------- async global->LDS ----------------
__device__ __forceinline__ void async_lds16(const u16* g, const u16* lds) {
  __builtin_amdgcn_global_load_lds(
      (const __attribute__((address_space(1))) u32*)g,
      (__attribute__((address_space(3))) u32*)lds, 16, 0, 0);
}

// ================== 8-phase 256x256 GLU GEMM ==================
// A = xb [T][1024], B = bc [E][4096][1024] (both K-contig bf16).
// LDS half-tile = [128 rows][64 k] bf16, XOR-swizzled: u16 col ^= (row&7)<<3.
// Stage: linear LDS dest + inverse-swizzled global source (both-sides rule).
__device__ __forceinline__ void stage_half(const u16* __restrict__ g, int ld,
                                           u16* l, int tid) {
#pragma unroll
  for (int j = 0; j < 2; j++) {
    int d16 = (j * 512 + tid) * 8;            // linear dest, lane-contiguous 16B
    int row = d16 >> 6;
    int col = (d16 & 63) ^ ((row & 7) << 3);  // pre-swizzled source col
    async_lds16(g + (size_t)row * ld + col, l + d16);
  }
}

__device__ __forceinline__ bf16x8 ldfrag(const u16* half_base, int row, int col) {
  return *reinterpret_cast<const bf16x8*>(half_base + row * 64 + (col ^ ((row & 7) << 3)));
}

// Phase = one 128x128 C-quadrant (QR,QC) x K=64, all 8 waves (2x4 within quadrant).
#define PHASE(QR, QC, ...)                                                   \
  {                                                                          \
    const u16* Ah = &lds_[buf][0][QR][0];                                    \
    const u16* Bh = &lds_[buf][1][QC][0];                                    \
    bf16x8 a_[4][2], b_[2][2];                                               \
    _Pragma("unroll") for (int m = 0; m < 4; m++)                            \
      _Pragma("unroll") for (int kk = 0; kk < 2; kk++)                       \
        a_[m][kk] = ldfrag(Ah, qr * 64 + m * 16 + fr, kk * 32 + kq);         \
    _Pragma("unroll") for (int n = 0; n < 2; n++)                            \
      _Pragma("unroll") for (int kk = 0; kk < 2; kk++)                       \
        b_[n][kk] = ldfrag(Bh, qc * 32 + n * 16 + fr, kk * 32 + kq);         \
    __VA_ARGS__;                                                             \
    __builtin_amdgcn_s_barrier();                                            \
    __builtin_amdgcn_s_setprio(1);                                           \
    _Pragma("unroll") for (int m = 0; m < 4; m++)                            \
      _Pragma("unroll") for (int n = 0; n < 2; n++) {                        \
        acc[QR][QC][m][n] = __builtin_amdgcn_mfma_f32_16x16x32_bf16(         \
            a_[m][0], b_[n][0], acc[QR][QC][m][n], 0, 0, 0);                 \
        acc[QR][QC][m][n] = __builtin_amdgcn_mfma_f32_16x16x32_bf16(         \
            a_[m][1], b_[n][1], acc[QR][QC][m][n], 0, 0, 0);                 \
      }                                                                      \
    __builtin_amdgcn_s_setprio(0);                                           \
  }

__launch_bounds__(512, 2)
__global__ void glu_gemm8(const u16* __restrict__ xb, const u16* __restrict__ bc,
                          u16* __restrict__ gb) {
  __shared__ __align__(16) u16 lds_[2][2][2][8192];  // [buf][A/B][half][128*64]

  // bijective XCD swizzle (512 blocks, 512%8==0): each XCD owns one expert
  const int wg = blockIdx.x;
  const int sw = (wg & 7) * 64 + (wg >> 3);
  const int e = sw >> 6;
  const int by = (sw >> 4) & 3;
  const int bx = sw & 15;
  const int m0 = e * TPE + by * 256;
  const int n0 = bx * 256;

  const int tid = threadIdx.x;
  const int lane = tid & 63;
  const int wid = tid >> 6;
  const int qr = wid >> 2;     // wave row within quadrant (0..1) -> 64 rows
  const int qc = wid & 3;      // wave col within quadrant (0..3) -> 32 cols
  const int fr = lane & 15;
  const int kq = (lane >> 4) * 8;

  const u16* Abase = xb + (size_t)m0 * NH;
  const u16* Bbase = bc + ((size_t)e * (2 * NF) + n0) * NH;

  f32x4 acc[2][2][4][2] = {};

  // prologue: tile0 all 4 halves + tile1.A0 + tile1.B1
  stage_half(Abase, NH, &lds_[0][0][0][0], tid);
  stage_half(Bbase, NH, &lds_[0][1][0][0], tid);
  stage_half(Bbase + (size_t)128 * NH, NH, &lds_[0][1][1][0], tid);
  stage_half(Abase + (size_t)128 * NH, NH, &lds_[0][0][1][0], tid);
  stage_half(Abase + 64, NH, &lds_[1][0][0][0], tid);
  stage_half(Bbase + (size_t)128 * NH + 64, NH, &lds_[1][1][1][0], tid);
  asm volatile("s_waitcnt vmcnt(4)" ::: "memory");
  __builtin_amdgcn_s_barrier();

  int buf = 0;
#pragma unroll 1
  for (int t = 0; t < NKT; t++) {
    const int nb = buf ^ 1;
    const u16* An = Abase + (t + 1) * 64;
    const u16* Bn = Bbase + (t + 1) * 64;
    const u16* An2 = Abase + (t + 2) * 64;
    const u16* Bn2 = Bbase + (t + 2) * 64;
    // quadrant order 00 -> 01 -> 11 -> 10 (A0 dies after P2, B1 after P3)
    PHASE(0, 0, if (t + 1 < NKT) stage_half(An + (size_t)128 * NH, NH, &lds_[nb][0][1][0], tid));
    __builtin_amdgcn_s_barrier();
    PHASE(0, 1, if (t + 1 < NKT) stage_half(Bn, NH, &lds_[nb][1][0][0], tid));
    __builtin_amdgcn_s_barrier();
    PHASE(1, 1, if (t + 2 < NKT) stage_half(An2, NH, &lds_[buf][0][0][0], tid));
    __builtin_amdgcn_s_barrier();
    PHASE(1, 0, if (t + 2 < NKT) stage_half(Bn2 + (size_t)128 * NH, NH, &lds_[buf][1][1][0], tid));
    if (t + 2 < NKT)      asm volatile("s_waitcnt vmcnt(4)" ::: "memory");
    else if (t + 1 < NKT) asm volatile("s_waitcnt vmcnt(0)" ::: "memory");
    __builtin_amdgcn_s_barrier();
    buf = nb;
  }

  // epilogue: GLU combine in-register (n=0 -> h1, n=1 -> h2 of same f cols)
  const int rq = (lane >> 4) * 4;
#pragma unroll
  for (int QR = 0; QR < 2; QR++)
#pragma unroll
    for (int QC = 0; QC < 2; QC++)
#pragma unroll
      for (int m = 0; m < 4; m++) {
        int row = m0 + QR * 128 + qr * 64 + m * 16 + rq;
        int f = ((n0 + QC * 128 + qc * 32) >> 1) + fr;
#pragma unroll
        for (int r = 0; r < 4; r++) {
          float h1 = acc[QR][QC][m][0][r];
          float h2 = acc[QR][QC][m][1][r];
          float g = 0.5f * h1 * (1.0f + erff(h1 * 0.70710678118654752f)) * h2;
          gb[(size_t)(row + r) * NF + f] = f2bf_rn(g);
        }
      }
}

// ================== down GEMM (2-phase 128x128, +2-way swizzle) ==================
// stage a [128][32] bf16 tile; swizzle: u16 col ^= ((row>>1)&3)<<3
__device__ __forceinline__ void stage_tile32(const u16* __restrict__ g_base, size_t ld,
                                             const u16* lds_base, int tid) {
#pragma unroll
  for (int p = 0; p < 2; p++) {
    int eo = (p * 256 + tid) * 8;
    int row = eo >> 5;
    int col = (eo & 31) ^ (((row >> 1) & 3) << 3);
    async_lds16(g_base + (size_t)row * ld + col, lds_base + eo);
  }
}

__device__ __forceinline__ bf16x8 ldfrag32(const u16* base, int row, int col) {
  return *reinterpret_cast<const bf16x8*>(base + row * 32 + (col ^ (((row >> 1) & 3) << 3)));
}

__launch_bounds__(256, 2)
__global__ void down_gemm(const u16* __restrict__ gb, const u16* __restrict__ w2tb,
                          float* __restrict__ out) {
  __shared__ __align__(16) u16 As[128 * 32];
  __shared__ __align__(16) u16 Bs[128 * 32];

  const int e = blockIdx.z;
  const int m0 = e * TPE + blockIdx.y * 128;
  const int n0 = blockIdx.x * 128;
  const int tid = threadIdx.x;
  const int lane = tid & 63;
  const int wid = tid >> 6;
  const int wr = (wid >> 1) * 64;
  const int wc = (wid & 1) * 64;

  const u16* Ag = gb + (size_t)m0 * NF;
  const u16* Bg = w2tb + ((size_t)e * NH + n0) * NF;

  f32x4 acc[4][4] = {};

  const int fr = lane & 15;
  const int kb = (lane >> 4) * 8;

  for (int k0 = 0; k0 < NF; k0 += 32) {
    __syncthreads();
    stage_tile32(Ag + k0, NF, As, tid);
    stage_tile32(Bg + k0, NF, Bs, tid);
    __syncthreads();

    bf16x8 a[4], b[4];
#pragma unroll
    for (int m = 0; m < 4; m++)
      a[m] = ldfrag32(As, wr + m * 16 + fr, kb);
#pragma unroll
    for (int n = 0; n < 4; n++)
      b[n] = ldfrag32(Bs, wc + n * 16 + fr, kb);
#pragma unroll
    for (int m = 0; m < 4; m++)
#pragma unroll
      for (int n = 0; n < 4; n++)
        acc[m][n] = __builtin_amdgcn_mfma_f32_16x16x32_bf16(a[m], b[n], acc[m][n], 0, 0, 0);
  }

  const int rq = (lane >> 4) * 4;
#pragma unroll
  for (int m = 0; m < 4; m++)
#pragma unroll
    for (int n = 0; n < 4; n++)
#pragma unroll
      for (int r = 0; r < 4; r++) {
        int grow = m0 + wr + m * 16 + rq + r;
        int gcol = n0 + wc + n * 16 + fr;
        out[(size_t)grow * NH + gcol] = acc[m][n][r];
      }
}

// ---------------- launch ----------------
extern "C" void kernel_launch(void* const* d_in, const int* in_sizes, int n_in,
                              void* d_out, int out_size, void* d_ws, size_t ws_size,
                              hipStream_t stream) {
  const float* x = (const float*)d_in[0];
  // d_in[1] = expert_idx (balanced, sorted -- not needed)
  const float* w1 = (const float*)d_in[2];
  const float* v1 = (const float*)d_in[3];
  const float* w2 = (const float*)d_in[4];
  float* out = (float*)d_out;

  char* ws = (char*)d_ws;
  u16* xb   = (u16*)(ws);                                  // 16 MB
  u16* bc   = (u16*)(ws + (size_t)16 * 1024 * 1024);       // 64 MB  B_cat
  u16* w2tb = (u16*)(ws + (size_t)80 * 1024 * 1024);       // 32 MB
  u16* gb   = (u16*)(ws + (size_t)112 * 1024 * 1024);      // 32 MB

  const int nx = NT * NH;          // 8M

  cvt_f32_bf16<<<nx / 4 / 256, 256, 0, stream>>>(x, xb, nx);
  pack_b<<<NE * 2 * NF, 256, 0, stream>>>(w1, v1, bc);
  transpose_w2<<<dim3(NH / 32, NF / 32, NE), dim3(32, 8, 1), 0, stream>>>(w2, w2tb);

  glu_gemm8<<<512, 512, 0, stream>>>(xb, bc, gb);
  down_gemm<<<dim3(NH / 128, TPE / 128, NE), 256, 0, stream>>>(gb, w2tb, out);
}

// Round 3
// 205.536 us; speedup vs baseline: 1.0498x; 1.0065x over previous
//
#include <hip/hip_runtime.h>
#include <hip/hip_bf16.h>
#include <cstdint>
#include <cstddef>

#define NE 8
#define NH 1024
#define NF 2048
#define NT 8192
#define TPE (NT / NE)   // 1024
#define NKT (NH / 64)   // 16 K-tiles for the GLU gemm

typedef uint16_t u16;
typedef uint32_t u32;
typedef __attribute__((ext_vector_type(8))) __bf16 bf16x8;
typedef __attribute__((ext_vector_type(4))) float f32x4;

__device__ __forceinline__ u16 f2bf_rn(float f) {
  u32 u = __float_as_uint(f);
  u32 r = (u + 0x7fffu + ((u >> 16) & 1u)) >> 16;
  return (u16)r;
}

// ---------------- fp32 -> bf16 elementwise convert (RNE) ----------------
__global__ void cvt_f32_bf16(const float* __restrict__ in, u16* __restrict__ out, int n) {
  int i = (blockIdx.x * blockDim.x + threadIdx.x) * 4;
  if (i < n) {
    float4 v = *reinterpret_cast<const float4*>(in + i);
    ushort4 o;
    o.x = f2bf_rn(v.x);
    o.y = f2bf_rn(v.y);
    o.z = f2bf_rn(v.z);
    o.w = f2bf_rn(v.w);
    *reinterpret_cast<ushort4*>(out + i) = o;
  }
}

// ---------------- w2 [E][F][H] fp32 -> w2t [E][H][F] bf16 ----------------
__global__ void transpose_w2(const float* __restrict__ w2, u16* __restrict__ w2t) {
  __shared__ float tile[32][33];
  const int e = blockIdx.z;
  const int h0 = blockIdx.x * 32;
  const int f0 = blockIdx.y * 32;
  const int tx = threadIdx.x, ty = threadIdx.y;  // 32 x 8
  const float* src = w2 + ((size_t)e * NF + f0) * NH + h0;
#pragma unroll
  for (int i = 0; i < 4; i++) {
    int r = ty + i * 8;
    tile[r][tx] = src[(size_t)r * NH + tx];
  }
  __syncthreads();
  u16* dst = w2t + ((size_t)e * NH + h0) * NF + f0;
#pragma unroll
  for (int i = 0; i < 4; i++) {
    int r = ty + i * 8;
    dst[(size_t)r * NF + tx] = f2bf_rn(tile[tx][r]);
  }
}

// ---------------- async global->LDS ----------------
__device__ __forceinline__ void async_lds16(const u16* g, const u16* lds) {
  __builtin_amdgcn_global_load_lds(
      (const __attribute__((address_space(1))) u32*)g,
      (__attribute__((address_space(3))) u32*)lds, 16, 0, 0);
}

// stage a [128 rows][64 k] bf16 half-tile via global_load_lds:
// linear LDS dest + inverse-swizzled global source (both-sides rule).
__device__ __forceinline__ void stage_half(const u16* __restrict__ g, int ld,
                                           u16* l, int tid) {
#pragma unroll
  for (int j = 0; j < 2; j++) {
    int d16 = (j * 512 + tid) * 8;            // linear dest, lane-contiguous 16B
    int row = d16 >> 6;
    int col = (d16 & 63) ^ ((row & 7) << 3);  // pre-swizzled source col
    async_lds16(g + (size_t)row * ld + col, l + d16);
  }
}

__device__ __forceinline__ bf16x8 ldfrag(const u16* half_base, int row, int col) {
  return *reinterpret_cast<const bf16x8*>(half_base + row * 64 + (col ^ ((row & 7) << 3)));
}

// branchless A&S 7.1.26: returns 1 + erf(s), |err| <= ~2e-7
__device__ __forceinline__ float one_plus_erf(float s) {
  float z = fabsf(s);
  float t = __builtin_amdgcn_rcpf(fmaf(0.3275911f, z, 1.0f));
  float p = t * fmaf(t, fmaf(t, fmaf(t, fmaf(t, 1.061405429f, -1.453152027f),
                                     1.421413741f), -0.284496736f), 0.254829592f);
  float pe = p * __expf(-z * z);
  return (s >= 0.0f) ? (2.0f - pe) : pe;
}

// Phase = one 128x128 C-quadrant (QR,QC) x K=64, all 8 waves (2x4 within quadrant).
#define PHASE(QR, QC, ...)                                                   \
  {                                                                          \
    const u16* Ah = &lds_[buf][0][QR][0];                                    \
    const u16* Bh = &lds_[buf][1][QC][0];                                    \
    bf16x8 a_[4][2], b_[2][2];                                               \
    _Pragma("unroll") for (int m = 0; m < 4; m++)                            \
      _Pragma("unroll") for (int kk = 0; kk < 2; kk++)                       \
        a_[m][kk] = ldfrag(Ah, qr * 64 + m * 16 + fr, kk * 32 + kq);         \
    _Pragma("unroll") for (int n = 0; n < 2; n++)                            \
      _Pragma("unroll") for (int kk = 0; kk < 2; kk++)                       \
        b_[n][kk] = ldfrag(Bh, qc * 32 + n * 16 + fr, kk * 32 + kq);         \
    __VA_ARGS__;                                                             \
    __builtin_amdgcn_s_barrier();                                            \
    __builtin_amdgcn_s_setprio(1);                                           \
    _Pragma("unroll") for (int m = 0; m < 4; m++)                            \
      _Pragma("unroll") for (int n = 0; n < 2; n++) {                        \
        acc[QR][QC][m][n] = __builtin_amdgcn_mfma_f32_16x16x32_bf16(         \
            a_[m][0], b_[n][0], acc[QR][QC][m][n], 0, 0, 0);                 \
        acc[QR][QC][m][n] = __builtin_amdgcn_mfma_f32_16x16x32_bf16(         \
            a_[m][1], b_[n][1], acc[QR][QC][m][n], 0, 0, 0);                 \
      }                                                                      \
    __builtin_amdgcn_s_setprio(0);                                           \
  }

// B staging: issue 4 float4 fp32 loads (issue-early), cvt+swizzled ds_write (write-late)
#define B_ISSUE(h, kt, dst)                                                  \
  {                                                                          \
    const float* s_ = Bsrc##h + (size_t)(kt) * 64 + scol;                    \
    dst[0] = *reinterpret_cast<const float4*>(s_);                           \
    dst[1] = *reinterpret_cast<const float4*>(s_ + 4);                       \
    dst[2] = *reinterpret_cast<const float4*>(s_ + 8);                       \
    dst[3] = *reinterpret_cast<const float4*>(s_ + 12);                      \
  }

#define B_WRITE(h, bufsel, dst)                                              \
  {                                                                          \
    u16* L_ = &lds_[bufsel][1][h][srow * 64];                                \
    const float* f_ = reinterpret_cast<const float*>(dst);                   \
    bf16x8 p0_, p1_;                                                         \
    _Pragma("unroll") for (int i_ = 0; i_ < 8; i_++) {                       \
      p0_[i_] = (__bf16)f_[i_];                                              \
      p1_[i_] = (__bf16)f_[8 + i_];                                          \
    }                                                                        \
    *reinterpret_cast<bf16x8*>(L_ + swA) = p0_;                              \
    *reinterpret_cast<bf16x8*>(L_ + swB) = p1_;                              \
  }

// ================== 8-phase 256x256 GLU GEMM, fused weight cvt ==================
// A = xb [T][1024] bf16. B-half0 = w1[e] rows [f0,f0+128) fp32, half1 = v1.
// acc[QR][0] = h1, acc[QR][1] = h2 of the SAME f columns.
__launch_bounds__(512, 2)
__global__ void glu_gemm8(const u16* __restrict__ xb, const float* __restrict__ w1,
                          const float* __restrict__ v1, u16* __restrict__ gb) {
  __shared__ __align__(16) u16 lds_[2][2][2][8192];  // [buf][A/B][half][128*64]

  // bijective XCD swizzle (512 blocks, 512%8==0)
  const int wg = blockIdx.x;
  const int sw = (wg & 7) * 64 + (wg >> 3);
  const int e = sw >> 6;
  const int by = (sw >> 4) & 3;
  const int bx = sw & 15;
  const int m0 = e * TPE + by * 256;
  const int f0 = bx * 128;

  const int tid = threadIdx.x;
  const int lane = tid & 63;
  const int wid = tid >> 6;
  const int qr = wid >> 2;     // wave row within quadrant (0..1) -> 64 rows
  const int qc = wid & 3;      // wave col within quadrant (0..3) -> 32 rows of B-half
  const int fr = lane & 15;
  const int kq = (lane >> 4) * 8;

  const u16* Abase = xb + (size_t)m0 * NH;
  // per-thread B staging geometry: thread -> (row, 16-col group)
  const int srow = tid >> 2;           // 0..127
  const int scol = (tid & 3) * 16;     // 0,16,32,48
  const int swA = scol ^ ((srow & 7) << 3);
  const int swB = (scol + 8) ^ ((srow & 7) << 3);
  const float* Bsrc0 = w1 + ((size_t)e * NF + f0 + srow) * NH;
  const float* Bsrc1 = v1 + ((size_t)e * NF + f0 + srow) * NH;

  f32x4 acc[2][2][4][2] = {};
  float4 rB[4];

  // ---- prologue: tile0 (B reg-staged, A gload) + t1.A0 gload ----
  B_ISSUE(0, 0, rB);
  float4 rB1[4];
  B_ISSUE(1, 0, rB1);
  stage_half(Abase, NH, &lds_[0][0][0][0], tid);
  stage_half(Abase + (size_t)128 * NH, NH, &lds_[0][0][1][0], tid);
  B_WRITE(0, 0, rB);
  B_WRITE(1, 0, rB1);
  stage_half(Abase + 64, NH, &lds_[1][0][0][0], tid);   // t1.A0
  asm volatile("s_waitcnt vmcnt(2) lgkmcnt(0)" ::: "memory");
  __builtin_amdgcn_s_barrier();

  int buf = 0;
#pragma unroll 1
  for (int t = 0; t < NKT; t++) {
    const int nb = buf ^ 1;
    const int kt1 = (t + 1 < NKT) ? t + 1 : NKT - 1;
    const int kt2 = (t + 2 < NKT) ? t + 2 : NKT - 1;
    // P1: Q00 | issue B0(t+1) loads, gload A1(t+1)->nb
    PHASE(0, 0, {
      B_ISSUE(0, kt1, rB);
      stage_half(Abase + (size_t)128 * NH + kt1 * 64, NH, &lds_[nb][0][1][0], tid);
    });
    __builtin_amdgcn_s_barrier();
    // P2: Q01 | cvt+write B0(t+1)->nb
    PHASE(0, 1, B_WRITE(0, nb, rB));
    __builtin_amdgcn_s_barrier();
    // P3: Q11 | issue B1(t+1) loads, gload A0(t+2)->buf
    PHASE(1, 1, {
      B_ISSUE(1, kt1, rB);
      stage_half(Abase + kt2 * 64, NH, &lds_[buf][0][0][0], tid);
    });
    __builtin_amdgcn_s_barrier();
    // P4: Q10 | cvt+write B1(t+1)->nb
    PHASE(1, 0, B_WRITE(1, nb, rB));
    asm volatile("s_waitcnt vmcnt(2) lgkmcnt(0)" ::: "memory");
    __builtin_amdgcn_s_barrier();
    buf = nb;
  }

  // epilogue: GLU in-register; QC=0 -> h1, QC=1 -> h2 of same f cols
  const int rq = (lane >> 4) * 4;
#pragma unroll
  for (int QR = 0; QR < 2; QR++)
#pragma unroll
    for (int m = 0; m < 4; m++) {
      int row = m0 + QR * 128 + qr * 64 + m * 16 + rq;
#pragma unroll
      for (int n = 0; n < 2; n++) {
        int f = f0 + qc * 32 + n * 16 + fr;
#pragma unroll
        for (int r = 0; r < 4; r++) {
          float h1 = acc[QR][0][m][n][r];
          float h2 = acc[QR][1][m][n][r];
          float g = 0.5f * h1 * one_plus_erf(h1 * 0.70710678118654752f) * h2;
          gb[(size_t)(row + r) * NF + f] = f2bf_rn(g);
        }
      }
    }
}

// ================== down GEMM (2-phase 128x128, +2-way swizzle) ==================
__device__ __forceinline__ void stage_tile32(const u16* __restrict__ g_base, size_t ld,
                                             const u16* lds_base, int tid) {
#pragma unroll
  for (int p = 0; p < 2; p++) {
    int eo = (p * 256 + tid) * 8;
    int row = eo >> 5;
    int col = (eo & 31) ^ (((row >> 1) & 3) << 3);
    async_lds16(g_base + (size_t)row * ld + col, lds_base + eo);
  }
}

__device__ __forceinline__ bf16x8 ldfrag32(const u16* base, int row, int col) {
  return *reinterpret_cast<const bf16x8*>(base + row * 32 + (col ^ (((row >> 1) & 3) << 3)));
}

__launch_bounds__(256, 2)
__global__ void down_gemm(const u16* __restrict__ gb, const u16* __restrict__ w2tb,
                          float* __restrict__ out) {
  __shared__ __align__(16) u16 As[128 * 32];
  __shared__ __align__(16) u16 Bs[128 * 32];

  const int e = blockIdx.z;
  const int m0 = e * TPE + blockIdx.y * 128;
  const int n0 = blockIdx.x * 128;
  const int tid = threadIdx.x;
  const int lane = tid & 63;
  const int wid = tid >> 6;
  const int wr = (wid >> 1) * 64;
  const int wc = (wid & 1) * 64;

  const u16* Ag = gb + (size_t)m0 * NF;
  const u16* Bg = w2tb + ((size_t)e * NH + n0) * NF;

  f32x4 acc[4][4] = {};

  const int fr = lane & 15;
  const int kb = (lane >> 4) * 8;

  for (int k0 = 0; k0 < NF; k0 += 32) {
    __syncthreads();
    stage_tile32(Ag + k0, NF, As, tid);
    stage_tile32(Bg + k0, NF, Bs, tid);
    __syncthreads();

    bf16x8 a[4], b[4];
#pragma unroll
    for (int m = 0; m < 4; m++)
      a[m] = ldfrag32(As, wr + m * 16 + fr, kb);
#pragma unroll
    for (int n = 0; n < 4; n++)
      b[n] = ldfrag32(Bs, wc + n * 16 + fr, kb);
#pragma unroll
    for (int m = 0; m < 4; m++)
#pragma unroll
      for (int n = 0; n < 4; n++)
        acc[m][n] = __builtin_amdgcn_mfma_f32_16x16x32_bf16(a[m], b[n], acc[m][n], 0, 0, 0);
  }

  const int rq = (lane >> 4) * 4;
#pragma unroll
  for (int m = 0; m < 4; m++)
#pragma unroll
    for (int n = 0; n < 4; n++)
#pragma unroll
      for (int r = 0; r < 4; r++) {
        int grow = m0 + wr + m * 16 + rq + r;
        int gcol = n0 + wc + n * 16 + fr;
        out[(size_t)grow * NH + gcol] = acc[m][n][r];
      }
}

// ---------------- launch ----------------
extern "C" void kernel_launch(void* const* d_in, const int* in_sizes, int n_in,
                              void* d_out, int out_size, void* d_ws, size_t ws_size,
                              hipStream_t stream) {
  const float* x = (const float*)d_in[0];
  // d_in[1] = expert_idx (balanced, sorted -- not needed)
  const float* w1 = (const float*)d_in[2];
  const float* v1 = (const float*)d_in[3];
  const float* w2 = (const float*)d_in[4];
  float* out = (float*)d_out;

  char* ws = (char*)d_ws;
  u16* xb   = (u16*)(ws);                                  // 16 MB
  u16* w2tb = (u16*)(ws + (size_t)16 * 1024 * 1024);       // 32 MB
  u16* gb   = (u16*)(ws + (size_t)48 * 1024 * 1024);       // 32 MB

  const int nx = NT * NH;          // 8M

  cvt_f32_bf16<<<nx / 4 / 256, 256, 0, stream>>>(x, xb, nx);
  transpose_w2<<<dim3(NH / 32, NF / 32, NE), dim3(32, 8, 1), 0, stream>>>(w2, w2tb);

  glu_gemm8<<<512, 512, 0, stream>>>(xb, w1, v1, gb);
  down_gemm<<<dim3(NH / 128, TPE / 128, NE), 256, 0, stream>>>(gb, w2tb, out);
}

// Round 4
// 174.545 us; speedup vs baseline: 1.2361x; 1.1776x over previous
//
#include <hip/hip_runtime.h>
#include <hip/hip_bf16.h>
#include <cstdint>
#include <cstddef>

#define NE 8
#define NH 1024
#define NF 2048
#define NT 8192
#define TPE (NT / NE)    // 1024
#define NKT (NH / 64)    // 16 K-tiles, glu gemm
#define NKT2 (NF / 64)   // 32 K-tiles, down gemm

typedef uint16_t u16;
typedef uint32_t u32;
typedef __attribute__((ext_vector_type(8))) __bf16 bf16x8;
typedef __attribute__((ext_vector_type(4))) float f32x4;

__device__ __forceinline__ u16 f2bf_rn(float f) {
  u32 u = __float_as_uint(f);
  u32 r = (u + 0x7fffu + ((u >> 16) & 1u)) >> 16;
  return (u16)r;
}

// ---------------- fp32 -> bf16 elementwise convert (RNE) ----------------
__global__ void cvt_f32_bf16(const float* __restrict__ in, u16* __restrict__ out, int n) {
  int i = (blockIdx.x * blockDim.x + threadIdx.x) * 4;
  if (i < n) {
    float4 v = *reinterpret_cast<const float4*>(in + i);
    ushort4 o;
    o.x = f2bf_rn(v.x);
    o.y = f2bf_rn(v.y);
    o.z = f2bf_rn(v.z);
    o.w = f2bf_rn(v.w);
    *reinterpret_cast<ushort4*>(out + i) = o;
  }
}

// ------- pack w1/v1 -> B_cat[e][4096][1024] bf16, 16-col interleave -------
__global__ void pack_b(const float* __restrict__ w1, const float* __restrict__ v1,
                       u16* __restrict__ bc) {
  int j = blockIdx.x;              // 0 .. NE*4096-1
  int e = j >> 12;
  int r = j & 4095;
  int p = r >> 5;
  int q = (r >> 4) & 1;
  int c = r & 15;
  const float* src = (q ? v1 : w1) + ((size_t)e * NF + p * 16 + c) * NH;
  u16* dst = bc + (size_t)j * NH;
  int i = threadIdx.x * 4;
  float4 v = *reinterpret_cast<const float4*>(src + i);
  ushort4 o;
  o.x = f2bf_rn(v.x);
  o.y = f2bf_rn(v.y);
  o.z = f2bf_rn(v.z);
  o.w = f2bf_rn(v.w);
  *reinterpret_cast<ushort4*>(dst + i) = o;
}

// ---------------- w2 [E][F][H] fp32 -> w2t [E][H][F] bf16 ----------------
__global__ void transpose_w2(const float* __restrict__ w2, u16* __restrict__ w2t) {
  __shared__ float tile[32][33];
  const int e = blockIdx.z;
  const int h0 = blockIdx.x * 32;
  const int f0 = blockIdx.y * 32;
  const int tx = threadIdx.x, ty = threadIdx.y;  // 32 x 8
  const float* src = w2 + ((size_t)e * NF + f0) * NH + h0;
#pragma unroll
  for (int i = 0; i < 4; i++) {
    int r = ty + i * 8;
    tile[r][tx] = src[(size_t)r * NH + tx];
  }
  __syncthreads();
  u16* dst = w2t + ((size_t)e * NH + h0) * NF + f0;
#pragma unroll
  for (int i = 0; i < 4; i++) {
    int r = ty + i * 8;
    dst[(size_t)r * NF + tx] = f2bf_rn(tile[tx][r]);
  }
}

// ---------------- async global->LDS ----------------
__device__ __forceinline__ void async_lds16(const u16* g, const u16* lds) {
  __builtin_amdgcn_global_load_lds(
      (const __attribute__((address_space(1))) u32*)g,
      (__attribute__((address_space(3))) u32*)lds, 16, 0, 0);
}

// stage a [128 rows][64 k] bf16 half-tile: linear LDS dest + inverse-swizzled src
__device__ __forceinline__ void stage_half(const u16* __restrict__ g, int ld,
                                           u16* l, int tid) {
#pragma unroll
  for (int j = 0; j < 2; j++) {
    int d16 = (j * 512 + tid) * 8;
    int row = d16 >> 6;
    int col = (d16 & 63) ^ ((row & 7) << 3);
    async_lds16(g + (size_t)row * ld + col, l + d16);
  }
}

__device__ __forceinline__ bf16x8 ldfrag(const u16* half_base, int row, int col) {
  return *reinterpret_cast<const bf16x8*>(half_base + row * 64 + (col ^ ((row & 7) << 3)));
}

// branchless A&S 7.1.26: returns 1 + erf(s)
__device__ __forceinline__ float one_plus_erf(float s) {
  float z = fabsf(s);
  float t = __builtin_amdgcn_rcpf(fmaf(0.3275911f, z, 1.0f));
  float p = t * fmaf(t, fmaf(t, fmaf(t, fmaf(t, 1.061405429f, -1.453152027f),
                                     1.421413741f), -0.284496736f), 0.254829592f);
  float pe = p * __expf(-z * z);
  return (s >= 0.0f) ? (2.0f - pe) : pe;
}

#define MFMA16(ACC, A, B)                                                      \
  _Pragma("unroll") for (int m = 0; m < 4; m++)                                \
    _Pragma("unroll") for (int n = 0; n < 2; n++) {                            \
      ACC[m][n] = __builtin_amdgcn_mfma_f32_16x16x32_bf16(A[m][0], B[n][0],    \
                                                          ACC[m][n], 0, 0, 0); \
      ACC[m][n] = __builtin_amdgcn_mfma_f32_16x16x32_bf16(A[m][1], B[n][1],    \
                                                          ACC[m][n], 0, 0, 0); \
    }

// ================== 8-phase 256x256 GLU GEMM (frag-carry) ==================
// A = xb [T][1024], B = bc [E][4096][1024]. Quadrant order 00->01->11->10;
// shared operand carried in registers: 24 ds_read_b128 / K-tile (was 48).
__launch_bounds__(512, 2)
__global__ void glu_gemm8(const u16* __restrict__ xb, const u16* __restrict__ bc,
                          u16* __restrict__ gb) {
  __shared__ __align__(16) u16 lds_[2][2][2][8192];  // [buf][A/B][half][128*64]

  const int wg = blockIdx.x;
  const int sw = (wg & 7) * 64 + (wg >> 3);   // bijective XCD swizzle (512 % 8 == 0)
  const int e = sw >> 6;
  const int by = (sw >> 4) & 3;
  const int bx = sw & 15;
  const int m0 = e * TPE + by * 256;
  const int n0 = bx * 256;

  const int tid = threadIdx.x;
  const int lane = tid & 63;
  const int wid = tid >> 6;
  const int qr = wid >> 2;
  const int qc = wid & 3;
  const int fr = lane & 15;
  const int kq = (lane >> 4) * 8;

  const u16* Abase = xb + (size_t)m0 * NH;
  const u16* Bbase = bc + ((size_t)e * (2 * NF) + n0) * NH;

  f32x4 acc[2][2][4][2] = {};

  // prologue: tile0 all halves + t1.A0 + t1.B1  (12 loads; vmcnt(4) certifies tile0)
  stage_half(Abase, NH, &lds_[0][0][0][0], tid);
  stage_half(Bbase, NH, &lds_[0][1][0][0], tid);
  stage_half(Bbase + (size_t)128 * NH, NH, &lds_[0][1][1][0], tid);
  stage_half(Abase + (size_t)128 * NH, NH, &lds_[0][0][1][0], tid);
  stage_half(Abase + 64, NH, &lds_[1][0][0][0], tid);
  stage_half(Bbase + (size_t)128 * NH + 64, NH, &lds_[1][1][1][0], tid);
  asm volatile("s_waitcnt vmcnt(4)" ::: "memory");
  __builtin_amdgcn_s_barrier();

  int buf = 0;
#pragma unroll 1
  for (int t = 0; t < NKT; t++) {
    const int nb = buf ^ 1;
    const u16* Ah0 = &lds_[buf][0][0][0];
    const u16* Ah1 = &lds_[buf][0][1][0];
    const u16* Bh0 = &lds_[buf][1][0][0];
    const u16* Bh1 = &lds_[buf][1][1][0];

    bf16x8 a_[4][2], b0_[2][2], b1_[2][2];

    // ---- P1: Q00 (read A0 + B0) | stage A1(t+1)->nb ----
#pragma unroll
    for (int m = 0; m < 4; m++)
#pragma unroll
      for (int kk = 0; kk < 2; kk++)
        a_[m][kk] = ldfrag(Ah0, qr * 64 + m * 16 + fr, kk * 32 + kq);
#pragma unroll
    for (int n = 0; n < 2; n++)
#pragma unroll
      for (int kk = 0; kk < 2; kk++)
        b0_[n][kk] = ldfrag(Bh0, qc * 32 + n * 16 + fr, kk * 32 + kq);
    if (t + 1 < NKT)
      stage_half(Abase + (size_t)128 * NH + (t + 1) * 64, NH, &lds_[nb][0][1][0], tid);
    __builtin_amdgcn_s_barrier();
    __builtin_amdgcn_s_setprio(1);
    MFMA16(acc[0][0], a_, b0_);
    __builtin_amdgcn_s_setprio(0);
    __builtin_amdgcn_s_barrier();

    // ---- P2: Q01 (read B1; reuse a_) | stage B0(t+1)->nb ----
#pragma unroll
    for (int n = 0; n < 2; n++)
#pragma unroll
      for (int kk = 0; kk < 2; kk++)
        b1_[n][kk] = ldfrag(Bh1, qc * 32 + n * 16 + fr, kk * 32 + kq);
    if (t + 1 < NKT)
      stage_half(Bbase + (t + 1) * 64, NH, &lds_[nb][1][0][0], tid);
    __builtin_amdgcn_s_barrier();
    __builtin_amdgcn_s_setprio(1);
    MFMA16(acc[0][1], a_, b1_);
    __builtin_amdgcn_s_setprio(0);
    __builtin_amdgcn_s_barrier();

    // ---- P3: Q11 (read A1; reuse b1_) | stage A0(t+2)->buf ----
#pragma unroll
    for (int m = 0; m < 4; m++)
#pragma unroll
      for (int kk = 0; kk < 2; kk++)
        a_[m][kk] = ldfrag(Ah1, qr * 64 + m * 16 + fr, kk * 32 + kq);
    if (t + 2 < NKT)
      stage_half(Abase + (t + 2) * 64, NH, &lds_[buf][0][0][0], tid);
    __builtin_amdgcn_s_barrier();
    __builtin_amdgcn_s_setprio(1);
    MFMA16(acc[1][1], a_, b1_);
    __builtin_amdgcn_s_setprio(0);
    __builtin_amdgcn_s_barrier();

    // ---- P4: Q10 (no reads; reuse a_=A1, b0_=B0) | stage B1(t+2)->buf ----
    if (t + 2 < NKT)
      stage_half(Bbase + (size_t)128 * NH + (t + 2) * 64, NH, &lds_[buf][1][1][0], tid);
    __builtin_amdgcn_s_barrier();
    __builtin_amdgcn_s_setprio(1);
    MFMA16(acc[1][0], a_, b0_);
    __builtin_amdgcn_s_setprio(0);
    if (t + 2 < NKT)      asm volatile("s_waitcnt vmcnt(4)" ::: "memory");
    else if (t + 1 < NKT) asm volatile("s_waitcnt vmcnt(0)" ::: "memory");
    __builtin_amdgcn_s_barrier();
    buf = nb;
  }

  // epilogue: GLU in-register (interleaved B_cat: n-frag pair = h1,h2 of same f)
  const int rq = (lane >> 4) * 4;
#pragma unroll
  for (int QR = 0; QR < 2; QR++)
#pragma unroll
    for (int QC = 0; QC < 2; QC++)
#pragma unroll
      for (int m = 0; m < 4; m++) {
        int row = m0 + QR * 128 + qr * 64 + m * 16 + rq;
        int f = ((n0 + QC * 128 + qc * 32) >> 1) + fr;
#pragma unroll
        for (int r = 0; r < 4; r++) {
          float h1 = acc[QR][QC][m][0][r];
          float h2 = acc[QR][QC][m][1][r];
          float g = 0.5f * h1 * one_plus_erf(h1 * 0.70710678118654752f) * h2;
          gb[(size_t)(row + r) * NF + f] = f2bf_rn(g);
        }
      }
}

// ================== down GEMM: 2-phase/K-tile, BM=128 BN=256, frag-carry ==================
// A = gb [8192][2048], B = w2t [E][1024][2048]. grid=256 (1 block/CU), K=2048.
__launch_bounds__(512, 2)
__global__ void down_gemm8(const u16* __restrict__ gb, const u16* __restrict__ w2tb,
                           float* __restrict__ out) {
  __shared__ __align__(16) u16 lds_[2][3][8192];  // [buf][A,B0,B1][128*64]

  const int wg = blockIdx.x;
  const int sw = (wg & 7) * 32 + (wg >> 3);   // bijective XCD swizzle (256 % 8 == 0)
  const int e = sw >> 5;                      // each XCD owns one expert
  const int loc = sw & 31;
  const int bm = loc >> 2;                    // 0..7 (128-row band within expert)
  const int bn = loc & 3;                     // 0..3 (256 h-cols)
  const int m0 = e * TPE + bm * 128;
  const int n0 = bn * 256;

  const int tid = threadIdx.x;
  const int lane = tid & 63;
  const int wid = tid >> 6;
  const int qr = wid >> 2;    // 0..1: 64-row band
  const int qc = wid & 3;     // 0..3: 32-col band within 128-col B-half
  const int fr = lane & 15;
  const int kq = (lane >> 4) * 8;

  const u16* Ab = gb + (size_t)m0 * NF;
  const u16* Bb = w2tb + ((size_t)e * NH + n0) * NF;

  f32x4 acc[2][4][2] = {};

  // prologue: tile0 (A, B0, B1) — vmcnt(2) certifies A,B0; B1 stays in flight
  stage_half(Ab, NF, &lds_[0][0][0], tid);
  stage_half(Bb, NF, &lds_[0][1][0], tid);
  stage_half(Bb + (size_t)128 * NF, NF, &lds_[0][2][0], tid);
  asm volatile("s_waitcnt vmcnt(2)" ::: "memory");
  __builtin_amdgcn_s_barrier();

  int buf = 0;
#pragma unroll 1
  for (int t = 0; t < NKT2; t++) {
    const int nb = buf ^ 1;
    bf16x8 a_[4][2], b_[2][2];

    // ---- P1: (A, B0) | stage A(t+1), B0(t+1) -> nb ----
#pragma unroll
    for (int m = 0; m < 4; m++)
#pragma unroll
      for (int kk = 0; kk < 2; kk++)
        a_[m][kk] = ldfrag(&lds_[buf][0][0], qr * 64 + m * 16 + fr, kk * 32 + kq);
#pragma unroll
    for (int n = 0; n < 2; n++)
#pragma unroll
      for (int kk = 0; kk < 2; kk++)
        b_[n][kk] = ldfrag(&lds_[buf][1][0], qc * 32 + n * 16 + fr, kk * 32 + kq);
    if (t + 1 < NKT2) {
      stage_half(Ab + (t + 1) * 64, NF, &lds_[nb][0][0], tid);
      stage_half(Bb + (t + 1) * 64, NF, &lds_[nb][1][0], tid);
    }
    __builtin_amdgcn_s_barrier();
    __builtin_amdgcn_s_setprio(1);
    MFMA16(acc[0], a_, b_);
    __builtin_amdgcn_s_setprio(0);
    if (t + 1 < NKT2) asm volatile("s_waitcnt vmcnt(4)" ::: "memory");
    else              asm volatile("s_waitcnt vmcnt(0)" ::: "memory");
    __builtin_amdgcn_s_barrier();

    // ---- P2: (A reuse, B1) | stage B1(t+1) -> nb ----
#pragma unroll
    for (int n = 0; n < 2; n++)
#pragma unroll
      for (int kk = 0; kk < 2; kk++)
        b_[n][kk] = ldfrag(&lds_[buf][2][0], qc * 32 + n * 16 + fr, kk * 32 + kq);
    if (t + 1 < NKT2)
      stage_half(Bb + (size_t)128 * NF + (t + 1) * 64, NF, &lds_[nb][2][0], tid);
    __builtin_amdgcn_s_barrier();
    __builtin_amdgcn_s_setprio(1);
    MFMA16(acc[1], a_, b_);
    __builtin_amdgcn_s_setprio(0);
    if (t + 1 < NKT2) asm volatile("s_waitcnt vmcnt(2)" ::: "memory");
    __builtin_amdgcn_s_barrier();
    buf = nb;
  }

  const int rq = (lane >> 4) * 4;
#pragma unroll
  for (int QC = 0; QC < 2; QC++)
#pragma unroll
    for (int m = 0; m < 4; m++) {
      int row = m0 + qr * 64 + m * 16 + rq;
#pragma unroll
      for (int n = 0; n < 2; n++) {
        int col = n0 + QC * 128 + qc * 32 + n * 16 + fr;
#pragma unroll
        for (int r = 0; r < 4; r++)
          out[(size_t)(row + r) * NH + col] = acc[QC][m][n][r];
      }
    }
}

// ---------------- launch ----------------
extern "C" void kernel_launch(void* const* d_in, const int* in_sizes, int n_in,
                              void* d_out, int out_size, void* d_ws, size_t ws_size,
                              hipStream_t stream) {
  const float* x = (const float*)d_in[0];
  // d_in[1] = expert_idx (balanced, sorted -- not needed)
  const float* w1 = (const float*)d_in[2];
  const float* v1 = (const float*)d_in[3];
  const float* w2 = (const float*)d_in[4];
  float* out = (float*)d_out;

  char* ws = (char*)d_ws;
  u16* xb   = (u16*)(ws);                                  // 16 MB
  u16* bc   = (u16*)(ws + (size_t)16 * 1024 * 1024);       // 64 MB  B_cat
  u16* w2tb = (u16*)(ws + (size_t)80 * 1024 * 1024);       // 32 MB
  u16* gb   = (u16*)(ws + (size_t)112 * 1024 * 1024);      // 32 MB

  const int nx = NT * NH;          // 8M

  cvt_f32_bf16<<<nx / 4 / 256, 256, 0, stream>>>(x, xb, nx);
  pack_b<<<NE * 2 * NF, 256, 0, stream>>>(w1, v1, bc);
  transpose_w2<<<dim3(NH / 32, NF / 32, NE), dim3(32, 8, 1), 0, stream>>>(w2, w2tb);

  glu_gemm8<<<512, 512, 0, stream>>>(xb, bc, gb);
  down_gemm8<<<256, 512, 0, stream>>>(gb, w2tb, out);
}